// Round 6
// baseline (908.923 us; speedup 1.0000x reference)
//
#include <hip/hip_runtime.h>
#include <math.h>

#define NUM_ENT  50000
#define NUM_REL  64
#define NUM_TRI  400000
#define DIN      128
#define CAP      64                      // per-tail bucket capacity (deg~Poisson(8))

#define GRID     1024                    // co-resident: 256 CU x 4 blocks/CU
                                         // (launch_bounds(256,4) => VGPR<=128 => 4 blocks/CU;
                                         //  LDS 32KB/block => 5 blocks/CU; min = 4)

// P0 tasks
#define PACK_BLOCKS  24                  // 24*256*8 = 49152 = 3*128*128
#define SMALL_BLOCKS 64
#define ZERO_BLOCKS  196                 // ceil(50000/256)
#define P0_TASKS     (PACK_BLOCKS + SMALL_BLOCKS + ZERO_BLOCKS)   // 284

// P1 tasks: [scat | gemm], all co-resident in one pass (978 <= 1024)
#define SCAT_TASKS   196                 // ceil(400000/2048): 8 triplets/thread
#define GEMM_TASKS   782                 // ceil(50000/64)
#define P1_TASKS     (SCAT_TASKS + GEMM_TASKS)                    // 978

// P2 tasks: 4 tails per block-pass
#define P2_TASKS     (NUM_ENT / 4)       // 12500

typedef __attribute__((ext_vector_type(8))) short bf16x8;
typedef __attribute__((ext_vector_type(8))) unsigned short u16x8;
typedef __attribute__((ext_vector_type(4))) float f32x4;

__device__ __forceinline__ float4 f4add(float4 a, float4 b) {
    return make_float4(a.x + b.x, a.y + b.y, a.z + b.z, a.w + b.w);
}

// fp32 -> bf16 bits, round-to-nearest-even
__device__ __forceinline__ unsigned short f2bf(float f) {
    unsigned u = __float_as_uint(f);
    unsigned r = ((u >> 16) & 1u) + 0x7fffu;
    return (unsigned short)((u + r) >> 16);
}
__device__ __forceinline__ float bf2f(unsigned short h) {
    return __uint_as_float(((unsigned)h) << 16);
}
__device__ __forceinline__ float4 ldbf4(const unsigned short* p) {
    ushort4 u = *(const ushort4*)p;
    return make_float4(bf2f(u.x), bf2f(u.y), bf2f(u.z), bf2f(u.w));
}
// load 8 interleaved bf16 with ONE 16B load -> two float4 (first 4, last 4)
__device__ __forceinline__ void ldbf8(const unsigned short* p, float4* lo, float4* hi) {
    u16x8 u = *(const u16x8*)p;
    *lo = make_float4(bf2f(u[0]), bf2f(u[1]), bf2f(u[2]), bf2f(u[3]));
    *hi = make_float4(bf2f(u[4]), bf2f(u[5]), bf2f(u[6]), bf2f(u[7]));
}

// tanh via fast exp + fast rcp; saturates exactly to +-1 on overflow
__device__ __forceinline__ float tanhf_fast(float x) {
    float e = __expf(2.f * x);
    return 1.f - 2.f * __builtin_amdgcn_rcpf(e + 1.f);
}
__device__ __forceinline__ float tanh_dot4(float4 x, float4 av) {
    return tanhf_fast(x.x) * av.x + tanhf_fast(x.y) * av.y +
           tanhf_fast(x.z) * av.z + tanhf_fast(x.w) * av.w;
}

// Software grid barrier for a fully co-resident regular launch.
// All blocks: release-fence, then thread 0 arrives (agent-scope add) and spins
// with acquire loads until `target` arrivals. Bounded spin = anti-hang valve.
__device__ __forceinline__ void grid_barrier(int* cnt, int target) {
    __threadfence();                                   // release my writes
    __syncthreads();
    if (threadIdx.x == 0) {
        __hip_atomic_fetch_add(cnt, 1, __ATOMIC_ACQ_REL, __HIP_MEMORY_SCOPE_AGENT);
        int spins = 0;
        while (__hip_atomic_load(cnt, __ATOMIC_ACQUIRE, __HIP_MEMORY_SCOPE_AGENT) < target) {
            __builtin_amdgcn_s_sleep(2);
            if (++spins > (1 << 26)) break;            // terminate instead of hang
        }
    }
    __syncthreads();
    __threadfence();                                   // acquire side: invalidate caches
}

// =====================================================================
// Mega-kernel (REGULAR launch): P0 prep -> bar -> P1 [scat || gemm] -> bar -> P2.
// One dispatch replaces 4: round-1/round-4 accounting showed ~15-20us of gap
// per dispatch boundary (~50-60us total).
// =====================================================================
__global__ __launch_bounds__(256, 4) void k_mega(
        const float* __restrict__ emb_ent,
        const float* __restrict__ emb_rel,
        const int*   __restrict__ trip,
        const float* __restrict__ Wa,
        const float* __restrict__ ba,
        const float* __restrict__ attn_vec,
        const float* __restrict__ Wg,
        const float* __restrict__ bg,
        float*       __restrict__ out,
        unsigned short* __restrict__ Pt,
        unsigned short* __restrict__ PhGh,
        unsigned short* __restrict__ TaTg,
        unsigned short* __restrict__ Bpack,
        int*  __restrict__ deg,
        int*  __restrict__ elist,
        int*  __restrict__ bar) {
    // 32KB LDS, phase-multiplexed: P0 small: float s[128]; P1 gemm: As[64][136];
    // P2: full TaTg cache (16384 us).
    __shared__ __align__(16) unsigned short LB[16384];

    int b = blockIdx.x;
    int tid = threadIdx.x;

    // ---------------- P0: [pack W frags | rel tables | zero deg] ----------------
    // Bpack flat index: (((s*8 + t)*4 + ks)*64 + lane)*8 + j
    //   holds W_s[k = ks*32 + (lane>>4)*8 + j][n = t*16 + (lane&15)] as bf16.
    // TaTg row r (256 us): pos 8*(n>>2)+(n&3) = Ta[n], pos 8*(n>>2)+4+(n&3) = Tg[n].
    if (b < PACK_BLOCKS) {
        for (int i = 0; i < 8; i++) {
            int idx = b * 2048 + i * 256 + tid;       // < 49152
            int j    = idx & 7;
            int lane = (idx >> 3) & 63;
            int ks   = (idx >> 9) & 3;
            int t    = (idx >> 11) & 7;
            int w    = idx >> 14;
            int k = ks * 32 + ((lane >> 4) << 3) + j;
            int n = t * 16 + (lane & 15);
            const float* W = (w == 0) ? Wa : (w == 1) ? (Wa + 128 * DIN) : Wg;
            Bpack[idx] = f2bf(W[k * DIN + n]);
        }
    } else if (b < PACK_BLOCKS + SMALL_BLOCKS) {
        float* s = (float*)LB;                        // 512B of the 32KB buffer
        int row = b - PACK_BLOCKS;
        if (tid < DIN) s[tid] = emb_rel[row * DIN + tid];
        __syncthreads();
        int j = tid & 127;
        const float* W = (tid < 128) ? (Wa + 256 * DIN) : (Wg + 128 * DIN);
        float acc = 0.f;
#pragma unroll 8
        for (int k = 0; k < DIN; k++) acc += s[k] * W[k * DIN + j];
        int pos = row * 256 + 8 * (j >> 2) + (j & 3) + ((tid < 128) ? 0 : 4);
        TaTg[pos] = f2bf(acc);
    } else if (b < P0_TASKS) {
        int idx = (b - PACK_BLOCKS - SMALL_BLOCKS) * 256 + tid;
        if (idx < NUM_ENT) deg[idx] = 0;
    }

    grid_barrier(bar, GRID);

    // ---------------- P1: [scat (196) | gemm (782)] all co-resident ----------------
    if (b < SCAT_TASKS) {
        // 8 triplets/thread via 6x int4, edge packed (h<<6)|r into a single int.
        int i0 = b * 2048 + tid * 8;                  // NUM_TRI % 8 == 0
        if (i0 < NUM_TRI) {
            const int4* tp = (const int4*)&trip[i0 * 3];   // 96B, 16B-aligned
            int4 A = tp[0], B4 = tp[1], C4 = tp[2], D4 = tp[3], E4 = tp[4], F4 = tp[5];
            int hs[8] = {A.x, A.w, B4.z, C4.y, D4.x, D4.w, E4.z, F4.y};
            int rs[8] = {A.y, B4.x, B4.w, C4.z, D4.y, E4.x, E4.w, F4.z};
            int ts[8] = {A.z, B4.y, C4.x, C4.w, D4.z, E4.y, F4.x, F4.w};
#pragma unroll
            for (int u = 0; u < 8; u++) {
                int pos = atomicAdd(&deg[ts[u]], 1);
                if (pos < CAP) elist[ts[u] * CAP + pos] = (hs[u] << 6) | rs[u];
            }
        }
    } else if (b < P1_TASKS) {
        // MFMA entity GEMM tile; operand-swapped, writes Pt (plain) and PhGh (interleaved).
        unsigned short (*As)[136] = (unsigned short (*)[136])LB;   // 8704 us of 16384
        int tile = b - SCAT_TASKS;
        int m0 = tile * 64;
        for (int i = 0; i < 8; i++) {
            int v = tid + i * 256;
            int row = v >> 5;
            int c4 = v & 31;
            int gr = m0 + row;
            if (gr >= NUM_ENT) gr = NUM_ENT - 1;
            float4 x = *(const float4*)&emb_ent[gr * DIN + c4 * 4];
            ushort4 h;
            h.x = f2bf(x.x); h.y = f2bf(x.y); h.z = f2bf(x.z); h.w = f2bf(x.w);
            *(ushort4*)&As[row][c4 * 4] = h;
        }
        __syncthreads();

        int w = tid >> 6;
        int q = tid & 63;
        int quad = q >> 4;
        int lrow = w * 16 + (q & 15);
        int gr = m0 + lrow;

        bf16x8 a[4];
#pragma unroll
        for (int ks = 0; ks < 4; ks++)
            a[ks] = *(const bf16x8*)&As[lrow][ks * 32 + quad * 8];

        const bf16x8* Bp = (const bf16x8*)Bpack;
#pragma unroll
        for (int s = 0; s < 3; s++) {
            f32x4 acc[8];
#pragma unroll
            for (int t = 0; t < 8; t++) acc[t] = (f32x4){0.f, 0.f, 0.f, 0.f};
#pragma unroll
            for (int ks = 0; ks < 4; ks++) {
#pragma unroll
                for (int t = 0; t < 8; t++) {
                    bf16x8 wf = Bp[((s * 8 + t) * 4 + ks) * 64 + q];
                    acc[t] = __builtin_amdgcn_mfma_f32_16x16x32_bf16(wf, a[ks], acc[t], 0, 0, 0);
                }
            }
            if (gr < NUM_ENT) {
#pragma unroll
                for (int t = 0; t < 8; t++) {
                    int n0 = t * 16 + quad * 4;        // n0 % 4 == 0
                    float4 bb = make_float4(0.f, 0.f, 0.f, 0.f);
                    if (s == 0) bb = *(const float4*)&ba[n0];
                    if (s == 2) bb = *(const float4*)&bg[n0];
                    ushort4 o;
                    o.x = f2bf(acc[t][0] + bb.x);
                    o.y = f2bf(acc[t][1] + bb.y);
                    o.z = f2bf(acc[t][2] + bb.z);
                    o.w = f2bf(acc[t][3] + bb.w);
                    if (s == 0) {
                        *(ushort4*)&Pt[gr * DIN + n0] = o;
                    } else {
                        *(ushort4*)&PhGh[gr * 256 + 2 * n0 + ((s == 1) ? 0 : 4)] = o;
                    }
                }
            }
        }
    }

    grid_barrier(bar, 2 * GRID);

    // ---------------- P2: fused per-tail pass, one 64-lane wave per tail ----------------
    // TaTg (32KB) staged once into LDS, reused across ~12 grid-stride passes.
    {
        uint4* dst = (uint4*)LB;
        const uint4* src = (const uint4*)TaTg;
#pragma unroll
        for (int i = 0; i < 8; i++) dst[tid + i * 256] = src[tid + i * 256];
    }
    __syncthreads();

    int wv = tid >> 6;
    int lane = tid & 63;
    int half = lane >> 5;
    int q = lane & 31;
    int c = q * 4;
    float4 av4 = *(const float4*)&attn_vec[c];

    // lanes 0-31 take even edges, 32-63 odd edges; merge is linear (exp-safe: |p|<=2).
    // SHFL-DIVERGENCE RULE: divergent-trip loop iterations are half0-only (reads its
    // own lanes: OK); the remainder can be half1-only, so its shfl MUST stay hoisted
    // to the reconverged point before the `if` (exec-masked-lane read is undefined --
    // produced absmax 2.39 when violated).
    for (int task = b; task < P2_TASKS; task += GRID) {
        int t = task * 4 + wv;
        int deg_t = deg[t];
        if (deg_t > CAP) deg_t = CAP;

        float4 pt4 = ldbf4(&Pt[t * DIN + c]);

        // whole bucket in one coalesced load; slots >= deg never selected
        int eall = elist[t * CAP + lane];

        float l = 0.f;
        float4 acc = make_float4(0.f, 0.f, 0.f, 0.f);
        float4 sTa = make_float4(0.f, 0.f, 0.f, 0.f);
        float4 sTg = make_float4(0.f, 0.f, 0.f, 0.f);

        int it = half;
        for (; it + 2 < deg_t; it += 4) {
            int e0 = __shfl(eall, it);
            int e1 = __shfl(eall, it + 2);
            int h0 = e0 >> 6, r0 = e0 & 63;
            int h1 = e1 >> 6, r1 = e1 & 63;
            float4 ta0, tg0, ph0, gh0, ta1, tg1, ph1, gh1;
            ldbf8(&LB[r0 * 256 + q * 8], &ta0, &tg0);
            ldbf8(&PhGh[h0 * 256 + q * 8], &ph0, &gh0);
            ldbf8(&LB[r1 * 256 + q * 8], &ta1, &tg1);
            ldbf8(&PhGh[h1 * 256 + q * 8], &ph1, &gh1);

            sTa = f4add(sTa, f4add(ta0, ta1));
            sTg = f4add(sTg, f4add(tg0, tg1));
            float4 pa0 = f4add(ph0, ta0);
            float4 gm0 = f4add(gh0, tg0);
            float4 pa1 = f4add(ph1, ta1);
            float4 gm1 = f4add(gh1, tg1);
            float p0 = tanh_dot4(f4add(pt4, pa0), av4);
            float p1 = tanh_dot4(f4add(pt4, pa1), av4);
            p0 += __shfl_xor(p0, 1);
            p0 += __shfl_xor(p0, 2);
            p1 += __shfl_xor(p1, 1);
            p1 += __shfl_xor(p1, 2);
            float w0 = __expf(p0);
            float w1 = __expf(p1);
            l += w0 + w1;
            acc.x += w0 * gm0.x + w1 * gm1.x;
            acc.y += w0 * gm0.y + w1 * gm1.y;
            acc.z += w0 * gm0.z + w1 * gm1.z;
            acc.w += w0 * gm0.w + w1 * gm1.w;
        }
        // remainder: shfl at reconverged control flow (all 64 lanes execute)
        {
            int e = __shfl(eall, it & (CAP - 1));
            if (it < deg_t) {
                int h = e >> 6;
                int r = e & 63;
                float4 ta, tg, ph, gh;
                ldbf8(&LB[r * 256 + q * 8], &ta, &tg);
                ldbf8(&PhGh[h * 256 + q * 8], &ph, &gh);
                sTa = f4add(sTa, ta);
                sTg = f4add(sTg, tg);
                float4 pa = f4add(ph, ta);
                float4 gm = f4add(gh, tg);
                float p = tanh_dot4(f4add(pt4, pa), av4);
                p += __shfl_xor(p, 1);
                p += __shfl_xor(p, 2);
                float w = __expf(p);
                l += w;
                acc.x += w * gm.x; acc.y += w * gm.y; acc.z += w * gm.z; acc.w += w * gm.w;
            }
        }

        // merge the two halves (linear: no running max needed)
        l     += __shfl_xor(l, 32);
        acc.x += __shfl_xor(acc.x, 32);
        acc.y += __shfl_xor(acc.y, 32);
        acc.z += __shfl_xor(acc.z, 32);
        acc.w += __shfl_xor(acc.w, 32);
        sTa.x += __shfl_xor(sTa.x, 32);
        sTa.y += __shfl_xor(sTa.y, 32);
        sTa.z += __shfl_xor(sTa.z, 32);
        sTa.w += __shfl_xor(sTa.w, 32);
        sTg.x += __shfl_xor(sTg.x, 32);
        sTg.y += __shfl_xor(sTg.y, 32);
        sTg.z += __shfl_xor(sTg.z, 32);
        sTg.w += __shfl_xor(sTg.w, 32);

        // self edge: both halves compute identical values (merged inputs)
        {
            float inv = (deg_t > 0) ? __builtin_amdgcn_rcpf((float)deg_t) : 0.f;
            float4 pa, gm;
            ldbf8(&PhGh[t * 256 + q * 8], &pa, &gm);
            pa.x += sTa.x * inv; pa.y += sTa.y * inv; pa.z += sTa.z * inv; pa.w += sTa.w * inv;
            gm.x += sTg.x * inv; gm.y += sTg.y * inv; gm.z += sTg.z * inv; gm.w += sTg.w * inv;
            float p = tanh_dot4(f4add(pt4, pa), av4);
            p += __shfl_xor(p, 1);
            p += __shfl_xor(p, 2);
            float w = __expf(p);
            l += w;
            acc.x += w * gm.x; acc.y += w * gm.y; acc.z += w * gm.z; acc.w += w * gm.w;
        }
        float invl = 1.f / (l + 1e-16f);
        if (half == 0) {
            *(float4*)&out[t * DIN + c] =
                make_float4(acc.x * invl, acc.y * invl, acc.z * invl, acc.w * invl);
        }
    }
}

extern "C" void kernel_launch(void* const* d_in, const int* in_sizes, int n_in,
                              void* d_out, int out_size, void* d_ws, size_t ws_size,
                              hipStream_t stream) {
    const float* emb_ent  = (const float*)d_in[0];
    const float* emb_rel  = (const float*)d_in[1];
    const int*   trip     = (const int*)d_in[2];
    const float* Wa       = (const float*)d_in[3];
    const float* ba       = (const float*)d_in[4];
    const float* attn_vec = (const float*)d_in[5];
    const float* Wg       = (const float*)d_in[6];
    const float* bg       = (const float*)d_in[7];
    float* out = (float*)d_out;

    // workspace layout: bf16 region then int region
    unsigned short* wsh = (unsigned short*)d_ws;
    unsigned short* Pt    = wsh;                      //  6,400,000 us
    unsigned short* PhGh  = wsh + 6400000;            // 12,800,000 us (interleaved)
    unsigned short* TaTg  = wsh + 19200000;           //     16,384 us (interleaved)
    unsigned short* Bpack = wsh + 19216384;           //     49,152
    int* deg   = (int*)(wsh + 19265536);              //     50,000 (zeroed in P0)
    int* elist = deg + 50000;                         // 50,000*64 int = 12.8 MB
    int* bar   = elist + NUM_ENT * CAP;               // 2 ints (barrier counter)
    // total ~ 51.6 MB

    hipMemsetAsync(bar, 0, 2 * sizeof(int), stream);

    k_mega<<<dim3(GRID), dim3(256), 0, stream>>>(
        emb_ent, emb_rel, trip, Wa, ba, attn_vec, Wg, bg, out,
        Pt, PhGh, TaTg, Bpack, deg, elist, bar);
}

// Round 7
// 543.594 us; speedup vs baseline: 1.6721x; 1.6721x over previous
//
#include <hip/hip_runtime.h>
#include <math.h>

#define NUM_ENT  50000
#define NUM_REL  64
#define NUM_TRI  400000
#define DIN      128
#define CAP      64                      // per-tail bucket capacity (deg~Poisson(8))

#define GRID     1024                    // co-resident: 256 CU x 4 blocks/CU
                                         // (launch_bounds(256,4) => VGPR<=128 => 4 blocks/CU;
                                         //  LDS 32KB/block => 5 blocks/CU; min = 4)
                                         // round-6 measured: 44 VGPR, occupancy 48% => resident.

// P0 tasks
#define PACK_BLOCKS  24                  // 24*256*8 = 49152 = 3*128*128
#define SMALL_BLOCKS 64
#define ZERO_BLOCKS  196                 // ceil(50000/256)
#define P0_TASKS     (PACK_BLOCKS + SMALL_BLOCKS + ZERO_BLOCKS)   // 284

// P1 tasks: [scat | gemm], all co-resident in one pass (978 <= 1024)
#define SCAT_TASKS   196                 // ceil(400000/2048): 8 triplets/thread
#define GEMM_TASKS   782                 // ceil(50000/64)
#define P1_TASKS     (SCAT_TASKS + GEMM_TASKS)                    // 978

// P2 tasks: 4 tails per block-pass
#define P2_TASKS     (NUM_ENT / 4)       // 12500

typedef __attribute__((ext_vector_type(8))) short bf16x8;
typedef __attribute__((ext_vector_type(8))) unsigned short u16x8;
typedef __attribute__((ext_vector_type(4))) float f32x4;

__device__ __forceinline__ float4 f4add(float4 a, float4 b) {
    return make_float4(a.x + b.x, a.y + b.y, a.z + b.z, a.w + b.w);
}

// fp32 -> bf16 bits, round-to-nearest-even
__device__ __forceinline__ unsigned short f2bf(float f) {
    unsigned u = __float_as_uint(f);
    unsigned r = ((u >> 16) & 1u) + 0x7fffu;
    return (unsigned short)((u + r) >> 16);
}
__device__ __forceinline__ float bf2f(unsigned short h) {
    return __uint_as_float(((unsigned)h) << 16);
}
__device__ __forceinline__ float4 ldbf4(const unsigned short* p) {
    ushort4 u = *(const ushort4*)p;
    return make_float4(bf2f(u.x), bf2f(u.y), bf2f(u.z), bf2f(u.w));
}
// load 8 interleaved bf16 with ONE 16B load -> two float4 (first 4, last 4)
__device__ __forceinline__ void ldbf8(const unsigned short* p, float4* lo, float4* hi) {
    u16x8 u = *(const u16x8*)p;
    *lo = make_float4(bf2f(u[0]), bf2f(u[1]), bf2f(u[2]), bf2f(u[3]));
    *hi = make_float4(bf2f(u[4]), bf2f(u[5]), bf2f(u[6]), bf2f(u[7]));
}

// attention dot with av folded in: sum_i tanh(x_i)*av_i
//   = sumAv + sum_i m2av_i * rcp(e^{2 x_i} + 1),   m2av = -2*av.
// Saturates correctly: x->+inf: rcp(inf)=0 -> av_i; x->-inf: rcp(1)=1 -> -av_i.
__device__ __forceinline__ float att_p(float4 x, float4 m2av, float sumAv) {
    float r0 = __builtin_amdgcn_rcpf(__expf(2.f * x.x) + 1.f);
    float r1 = __builtin_amdgcn_rcpf(__expf(2.f * x.y) + 1.f);
    float r2 = __builtin_amdgcn_rcpf(__expf(2.f * x.z) + 1.f);
    float r3 = __builtin_amdgcn_rcpf(__expf(2.f * x.w) + 1.f);
    return fmaf(m2av.x, r0, fmaf(m2av.y, r1, fmaf(m2av.z, r2, fmaf(m2av.w, r3, sumAv))));
}

// Software grid barrier, co-resident launch. Round-6 post-mortem: polling with
// ACQUIRE at agent scope emits a cache-invalidate PER POLL (agent coherence point
// is past L2 on multi-XCD) -> 1024 spinners thrashed every XCD L2 -> 350us/barrier.
// Fix: RELAXED polls (plain coherent-point load, no invalidation), one acquire
// fence on exit. Release side unchanged (L2 writeback is required for cross-XCD
// visibility and happens once).
__device__ __forceinline__ void grid_barrier(int* cnt, int target) {
    __syncthreads();
    if (threadIdx.x == 0) {
        __threadfence();                               // release my block's writes
        __hip_atomic_fetch_add(cnt, 1, __ATOMIC_RELEASE, __HIP_MEMORY_SCOPE_AGENT);
        int spins = 0;
        while (__hip_atomic_load(cnt, __ATOMIC_RELAXED, __HIP_MEMORY_SCOPE_AGENT) < target) {
            __builtin_amdgcn_s_sleep(32);              // ~2k cycles between polls
            if (++spins > (1 << 20)) break;            // terminate instead of hang
        }
    }
    __syncthreads();
    __threadfence();                                   // acquire once: drop stale cache
}

// =====================================================================
// Mega-kernel (regular launch): P0 prep -> bar -> P1 [scat || gemm] -> bar -> P2.
// One dispatch replaces 4 (~15us gap each, round-1/round-4 accounting).
// Correctness of this exact phase structure verified in round 6 (absmax 0.015625).
// =====================================================================
__global__ __launch_bounds__(256, 4) void k_mega(
        const float* __restrict__ emb_ent,
        const float* __restrict__ emb_rel,
        const int*   __restrict__ trip,
        const float* __restrict__ Wa,
        const float* __restrict__ ba,
        const float* __restrict__ attn_vec,
        const float* __restrict__ Wg,
        const float* __restrict__ bg,
        float*       __restrict__ out,
        unsigned short* __restrict__ Pt,
        unsigned short* __restrict__ PhGh,
        unsigned short* __restrict__ TaTg,
        unsigned short* __restrict__ Bpack,
        int*  __restrict__ deg,
        int*  __restrict__ elist,
        int*  __restrict__ bar) {
    // 32KB LDS, phase-multiplexed: P0 small: float s[128]; P1 gemm: As[64][136];
    // P2: full TaTg cache (16384 us).
    __shared__ __align__(16) unsigned short LB[16384];

    int b = blockIdx.x;
    int tid = threadIdx.x;

    // ---------------- P0: [pack W frags | rel tables | zero deg] ----------------
    // Bpack flat index: (((s*8 + t)*4 + ks)*64 + lane)*8 + j
    //   holds W_s[k = ks*32 + (lane>>4)*8 + j][n = t*16 + (lane&15)] as bf16.
    // TaTg row r (256 us): pos 8*(n>>2)+(n&3) = Ta[n], pos 8*(n>>2)+4+(n&3) = Tg[n].
    if (b < PACK_BLOCKS) {
        for (int i = 0; i < 8; i++) {
            int idx = b * 2048 + i * 256 + tid;       // < 49152
            int j    = idx & 7;
            int lane = (idx >> 3) & 63;
            int ks   = (idx >> 9) & 3;
            int t    = (idx >> 11) & 7;
            int w    = idx >> 14;
            int k = ks * 32 + ((lane >> 4) << 3) + j;
            int n = t * 16 + (lane & 15);
            const float* W = (w == 0) ? Wa : (w == 1) ? (Wa + 128 * DIN) : Wg;
            Bpack[idx] = f2bf(W[k * DIN + n]);
        }
    } else if (b < PACK_BLOCKS + SMALL_BLOCKS) {
        float* s = (float*)LB;                        // 512B of the 32KB buffer
        int row = b - PACK_BLOCKS;
        if (tid < DIN) s[tid] = emb_rel[row * DIN + tid];
        __syncthreads();
        int j = tid & 127;
        const float* W = (tid < 128) ? (Wa + 256 * DIN) : (Wg + 128 * DIN);
        float acc = 0.f;
#pragma unroll 8
        for (int k = 0; k < DIN; k++) acc += s[k] * W[k * DIN + j];
        int pos = row * 256 + 8 * (j >> 2) + (j & 3) + ((tid < 128) ? 0 : 4);
        TaTg[pos] = f2bf(acc);
    } else if (b < P0_TASKS) {
        int idx = (b - PACK_BLOCKS - SMALL_BLOCKS) * 256 + tid;
        if (idx < NUM_ENT) deg[idx] = 0;
    }

    grid_barrier(bar, GRID);

    // ---------------- P1: [scat (196) | gemm (782)] all co-resident ----------------
    if (b < SCAT_TASKS) {
        // 8 triplets/thread via 6x int4, edge packed (h<<6)|r into a single int.
        int i0 = b * 2048 + tid * 8;                  // NUM_TRI % 8 == 0
        if (i0 < NUM_TRI) {
            const int4* tp = (const int4*)&trip[i0 * 3];   // 96B, 16B-aligned
            int4 A = tp[0], B4 = tp[1], C4 = tp[2], D4 = tp[3], E4 = tp[4], F4 = tp[5];
            int hs[8] = {A.x, A.w, B4.z, C4.y, D4.x, D4.w, E4.z, F4.y};
            int rs[8] = {A.y, B4.x, B4.w, C4.z, D4.y, E4.x, E4.w, F4.z};
            int ts[8] = {A.z, B4.y, C4.x, C4.w, D4.z, E4.y, F4.x, F4.w};
#pragma unroll
            for (int u = 0; u < 8; u++) {
                int pos = atomicAdd(&deg[ts[u]], 1);
                if (pos < CAP) elist[ts[u] * CAP + pos] = (hs[u] << 6) | rs[u];
            }
        }
    } else if (b < P1_TASKS) {
        // MFMA entity GEMM tile; operand-swapped, writes Pt (plain) and PhGh (interleaved).
        unsigned short (*As)[136] = (unsigned short (*)[136])LB;   // 8704 us of 16384
        int tile = b - SCAT_TASKS;
        int m0 = tile * 64;
        for (int i = 0; i < 8; i++) {
            int v = tid + i * 256;
            int row = v >> 5;
            int c4 = v & 31;
            int gr = m0 + row;
            if (gr >= NUM_ENT) gr = NUM_ENT - 1;
            float4 x = *(const float4*)&emb_ent[gr * DIN + c4 * 4];
            ushort4 h;
            h.x = f2bf(x.x); h.y = f2bf(x.y); h.z = f2bf(x.z); h.w = f2bf(x.w);
            *(ushort4*)&As[row][c4 * 4] = h;
        }
        __syncthreads();

        int w = tid >> 6;
        int q = tid & 63;
        int quad = q >> 4;
        int lrow = w * 16 + (q & 15);
        int gr = m0 + lrow;

        bf16x8 a[4];
#pragma unroll
        for (int ks = 0; ks < 4; ks++)
            a[ks] = *(const bf16x8*)&As[lrow][ks * 32 + quad * 8];

        const bf16x8* Bp = (const bf16x8*)Bpack;
#pragma unroll
        for (int s = 0; s < 3; s++) {
            f32x4 acc[8];
#pragma unroll
            for (int t = 0; t < 8; t++) acc[t] = (f32x4){0.f, 0.f, 0.f, 0.f};
#pragma unroll
            for (int ks = 0; ks < 4; ks++) {
#pragma unroll
                for (int t = 0; t < 8; t++) {
                    bf16x8 wf = Bp[((s * 8 + t) * 4 + ks) * 64 + q];
                    acc[t] = __builtin_amdgcn_mfma_f32_16x16x32_bf16(wf, a[ks], acc[t], 0, 0, 0);
                }
            }
            if (gr < NUM_ENT) {
#pragma unroll
                for (int t = 0; t < 8; t++) {
                    int n0 = t * 16 + quad * 4;        // n0 % 4 == 0
                    float4 bb = make_float4(0.f, 0.f, 0.f, 0.f);
                    if (s == 0) bb = *(const float4*)&ba[n0];
                    if (s == 2) bb = *(const float4*)&bg[n0];
                    ushort4 o;
                    o.x = f2bf(acc[t][0] + bb.x);
                    o.y = f2bf(acc[t][1] + bb.y);
                    o.z = f2bf(acc[t][2] + bb.z);
                    o.w = f2bf(acc[t][3] + bb.w);
                    if (s == 0) {
                        *(ushort4*)&Pt[gr * DIN + n0] = o;
                    } else {
                        *(ushort4*)&PhGh[gr * 256 + 2 * n0 + ((s == 1) ? 0 : 4)] = o;
                    }
                }
            }
        }
    }

    grid_barrier(bar, 2 * GRID);

    // ---------------- P2: fused per-tail pass, one 64-lane wave per tail ----------------
    // TaTg (32KB) staged once into LDS, reused across ~12 grid-stride passes.
    {
        uint4* dst = (uint4*)LB;
        const uint4* src = (const uint4*)TaTg;
#pragma unroll
        for (int i = 0; i < 8; i++) dst[tid + i * 256] = src[tid + i * 256];
    }
    __syncthreads();

    int wv = tid >> 6;
    int lane = tid & 63;
    int half = lane >> 5;
    int q = lane & 31;
    int c = q * 4;
    float4 av4 = *(const float4*)&attn_vec[c];
    float sumAv = av4.x + av4.y + av4.z + av4.w;
    float4 m2av = make_float4(-2.f * av4.x, -2.f * av4.y, -2.f * av4.z, -2.f * av4.w);

    // lanes 0-31 take even edges, 32-63 odd edges; merge is linear (exp-safe: |p|<=2).
    // SHFL-DIVERGENCE RULE: divergent-trip loop iterations are half0-only (reads its
    // own lanes: OK); the remainder can be half1-only, so its shfl MUST stay hoisted
    // to the reconverged point before the `if` (exec-masked-lane read is undefined --
    // produced absmax 2.39 when violated).
    for (int task = b; task < P2_TASKS; task += GRID) {
        int t = task * 4 + wv;
        int deg_t = deg[t];
        if (deg_t > CAP) deg_t = CAP;

        float4 pt4 = ldbf4(&Pt[t * DIN + c]);

        // whole bucket in one coalesced load; slots >= deg never selected
        int eall = elist[t * CAP + lane];

        float l = 0.f;
        float4 acc = make_float4(0.f, 0.f, 0.f, 0.f);
        float4 sTa = make_float4(0.f, 0.f, 0.f, 0.f);
        float4 sTg = make_float4(0.f, 0.f, 0.f, 0.f);

        int it = half;
        for (; it + 2 < deg_t; it += 4) {
            int e0 = __shfl(eall, it);
            int e1 = __shfl(eall, it + 2);
            int h0 = e0 >> 6, r0 = e0 & 63;
            int h1 = e1 >> 6, r1 = e1 & 63;
            float4 ta0, tg0, ph0, gh0, ta1, tg1, ph1, gh1;
            ldbf8(&LB[r0 * 256 + q * 8], &ta0, &tg0);
            ldbf8(&PhGh[h0 * 256 + q * 8], &ph0, &gh0);
            ldbf8(&LB[r1 * 256 + q * 8], &ta1, &tg1);
            ldbf8(&PhGh[h1 * 256 + q * 8], &ph1, &gh1);

            sTa = f4add(sTa, f4add(ta0, ta1));
            sTg = f4add(sTg, f4add(tg0, tg1));
            float4 pa0 = f4add(ph0, ta0);
            float4 gm0 = f4add(gh0, tg0);
            float4 pa1 = f4add(ph1, ta1);
            float4 gm1 = f4add(gh1, tg1);
            float p0 = att_p(f4add(pt4, pa0), m2av, sumAv);
            float p1 = att_p(f4add(pt4, pa1), m2av, sumAv);
            p0 += __shfl_xor(p0, 1);
            p0 += __shfl_xor(p0, 2);
            p1 += __shfl_xor(p1, 1);
            p1 += __shfl_xor(p1, 2);
            float w0 = __expf(p0);
            float w1 = __expf(p1);
            l += w0 + w1;
            acc.x += w0 * gm0.x + w1 * gm1.x;
            acc.y += w0 * gm0.y + w1 * gm1.y;
            acc.z += w0 * gm0.z + w1 * gm1.z;
            acc.w += w0 * gm0.w + w1 * gm1.w;
        }
        // remainder: shfl at reconverged control flow (all 64 lanes execute)
        {
            int e = __shfl(eall, it & (CAP - 1));
            if (it < deg_t) {
                int h = e >> 6;
                int r = e & 63;
                float4 ta, tg, ph, gh;
                ldbf8(&LB[r * 256 + q * 8], &ta, &tg);
                ldbf8(&PhGh[h * 256 + q * 8], &ph, &gh);
                sTa = f4add(sTa, ta);
                sTg = f4add(sTg, tg);
                float4 pa = f4add(ph, ta);
                float4 gm = f4add(gh, tg);
                float p = att_p(f4add(pt4, pa), m2av, sumAv);
                p += __shfl_xor(p, 1);
                p += __shfl_xor(p, 2);
                float w = __expf(p);
                l += w;
                acc.x += w * gm.x; acc.y += w * gm.y; acc.z += w * gm.z; acc.w += w * gm.w;
            }
        }

        // merge the two halves (linear: no running max needed)
        l     += __shfl_xor(l, 32);
        acc.x += __shfl_xor(acc.x, 32);
        acc.y += __shfl_xor(acc.y, 32);
        acc.z += __shfl_xor(acc.z, 32);
        acc.w += __shfl_xor(acc.w, 32);
        sTa.x += __shfl_xor(sTa.x, 32);
        sTa.y += __shfl_xor(sTa.y, 32);
        sTa.z += __shfl_xor(sTa.z, 32);
        sTa.w += __shfl_xor(sTa.w, 32);
        sTg.x += __shfl_xor(sTg.x, 32);
        sTg.y += __shfl_xor(sTg.y, 32);
        sTg.z += __shfl_xor(sTg.z, 32);
        sTg.w += __shfl_xor(sTg.w, 32);

        // self edge: both halves compute identical values (merged inputs)
        {
            float inv = (deg_t > 0) ? __builtin_amdgcn_rcpf((float)deg_t) : 0.f;
            float4 pa, gm;
            ldbf8(&PhGh[t * 256 + q * 8], &pa, &gm);
            pa.x += sTa.x * inv; pa.y += sTa.y * inv; pa.z += sTa.z * inv; pa.w += sTa.w * inv;
            gm.x += sTg.x * inv; gm.y += sTg.y * inv; gm.z += sTg.z * inv; gm.w += sTg.w * inv;
            float p = att_p(f4add(pt4, pa), m2av, sumAv);
            p += __shfl_xor(p, 1);
            p += __shfl_xor(p, 2);
            float w = __expf(p);
            l += w;
            acc.x += w * gm.x; acc.y += w * gm.y; acc.z += w * gm.z; acc.w += w * gm.w;
        }
        float invl = 1.f / (l + 1e-16f);
        if (half == 0) {
            *(float4*)&out[t * DIN + c] =
                make_float4(acc.x * invl, acc.y * invl, acc.z * invl, acc.w * invl);
        }
    }
}

extern "C" void kernel_launch(void* const* d_in, const int* in_sizes, int n_in,
                              void* d_out, int out_size, void* d_ws, size_t ws_size,
                              hipStream_t stream) {
    const float* emb_ent  = (const float*)d_in[0];
    const float* emb_rel  = (const float*)d_in[1];
    const int*   trip     = (const int*)d_in[2];
    const float* Wa       = (const float*)d_in[3];
    const float* ba       = (const float*)d_in[4];
    const float* attn_vec = (const float*)d_in[5];
    const float* Wg       = (const float*)d_in[6];
    const float* bg       = (const float*)d_in[7];
    float* out = (float*)d_out;

    // workspace layout: bf16 region then int region
    unsigned short* wsh = (unsigned short*)d_ws;
    unsigned short* Pt    = wsh;                      //  6,400,000 us
    unsigned short* PhGh  = wsh + 6400000;            // 12,800,000 us (interleaved)
    unsigned short* TaTg  = wsh + 19200000;           //     16,384 us (interleaved)
    unsigned short* Bpack = wsh + 19216384;           //     49,152
    int* deg   = (int*)(wsh + 19265536);              //     50,000 (zeroed in P0)
    int* elist = deg + 50000;                         // 50,000*64 int = 12.8 MB
    int* bar   = elist + NUM_ENT * CAP;               // 2 ints (barrier counter)
    // total ~ 51.6 MB

    hipMemsetAsync(bar, 0, 2 * sizeof(int), stream);

    k_mega<<<dim3(GRID), dim3(256), 0, stream>>>(
        emb_ent, emb_rel, trip, Wa, ba, attn_vec, Wg, bg, out,
        Pt, PhGh, TaTg, Bpack, deg, elist, bar);
}

// Round 8
// 184.292 us; speedup vs baseline: 4.9320x; 2.9496x over previous
//
#include <hip/hip_runtime.h>
#include <math.h>

#define NUM_ENT  50000
#define NUM_REL  64
#define NUM_TRI  400000
#define DIN      128
#define CAP      64                      // per-tail bucket capacity (deg~Poisson(8))

#define DEGS     16                      // deg counter stride in ints: 1 per 64B line
                                         // (atomics to same line serialize at the
                                         //  coherent point; 4B-packed counters put
                                         //  16 tails/line -> up to 128 serial ops)

// K1 partitions (deg zeroing moved to hipMemsetAsync)
#define PACK_BLOCKS  24                  // 24*256*8 = 49152 = 3*128*128
#define SMALL_BLOCKS 64
#define PREP_BLOCKS  (PACK_BLOCKS + SMALL_BLOCKS)     // 88

// K2 partitions: [gemm | scat] merged (scat latency hides under GEMM)
#define ENT_BLOCKS   782                 // ceil(50000/64)
#define SCAT_BLOCKS  391                 // ceil(400000/1024): 4 triplets/thread
#define MID_BLOCKS   (ENT_BLOCKS + SCAT_BLOCKS)

typedef __attribute__((ext_vector_type(8))) short bf16x8;
typedef __attribute__((ext_vector_type(8))) unsigned short u16x8;
typedef __attribute__((ext_vector_type(4))) float f32x4;

__device__ __forceinline__ float4 f4add(float4 a, float4 b) {
    return make_float4(a.x + b.x, a.y + b.y, a.z + b.z, a.w + b.w);
}

// fp32 -> bf16 bits, round-to-nearest-even
__device__ __forceinline__ unsigned short f2bf(float f) {
    unsigned u = __float_as_uint(f);
    unsigned r = ((u >> 16) & 1u) + 0x7fffu;
    return (unsigned short)((u + r) >> 16);
}
__device__ __forceinline__ float bf2f(unsigned short h) {
    return __uint_as_float(((unsigned)h) << 16);
}
__device__ __forceinline__ float4 ldbf4(const unsigned short* p) {
    ushort4 u = *(const ushort4*)p;
    return make_float4(bf2f(u.x), bf2f(u.y), bf2f(u.z), bf2f(u.w));
}
// load 8 interleaved bf16 with ONE 16B load -> two float4 (first 4, last 4)
__device__ __forceinline__ void ldbf8(const unsigned short* p, float4* lo, float4* hi) {
    u16x8 u = *(const u16x8*)p;
    *lo = make_float4(bf2f(u[0]), bf2f(u[1]), bf2f(u[2]), bf2f(u[3]));
    *hi = make_float4(bf2f(u[4]), bf2f(u[5]), bf2f(u[6]), bf2f(u[7]));
}

// attention dot with av folded in: sum_i tanh(x_i)*av_i
//   = sumAv + sum_i m2av_i * rcp(e^{2 x_i} + 1),   m2av = -2*av.
// Saturates correctly: x->+inf: rcp(inf)=0 -> av_i; x->-inf: rcp(1)=1 -> -av_i.
// Correctness validated round 7 (absmax 0.015625).
__device__ __forceinline__ float att_p(float4 x, float4 m2av, float sumAv) {
    float r0 = __builtin_amdgcn_rcpf(__expf(2.f * x.x) + 1.f);
    float r1 = __builtin_amdgcn_rcpf(__expf(2.f * x.y) + 1.f);
    float r2 = __builtin_amdgcn_rcpf(__expf(2.f * x.z) + 1.f);
    float r3 = __builtin_amdgcn_rcpf(__expf(2.f * x.w) + 1.f);
    return fmaf(m2av.x, r0, fmaf(m2av.y, r1, fmaf(m2av.z, r2, fmaf(m2av.w, r3, sumAv))));
}

// ---------------- K1: [pack W frags | rel tables (interleaved)] ----------
// Bpack flat index: (((s*8 + t)*4 + ks)*64 + lane)*8 + j
//   holds W_s[k = ks*32 + (lane>>4)*8 + j][n = t*16 + (lane&15)] as bf16.
// TaTg row r (256 us): pos 8*(n>>2)+(n&3) = Ta[n], pos 8*(n>>2)+4+(n&3) = Tg[n].
__global__ __launch_bounds__(256) void k_prep(const float* __restrict__ emb_rel,
                                              const float* __restrict__ Wa,
                                              const float* __restrict__ Wg,
                                              unsigned short* __restrict__ Bpack,
                                              unsigned short* __restrict__ TaTg) {
    __shared__ float s[DIN];
    int b = blockIdx.x;
    int tid = threadIdx.x;

    if (b < PACK_BLOCKS) {
        for (int i = 0; i < 8; i++) {
            int idx = b * 2048 + i * 256 + tid;       // < 49152
            int j    = idx & 7;
            int lane = (idx >> 3) & 63;
            int ks   = (idx >> 9) & 3;
            int t    = (idx >> 11) & 7;
            int w    = idx >> 14;
            int k = ks * 32 + ((lane >> 4) << 3) + j;
            int n = t * 16 + (lane & 15);
            const float* W = (w == 0) ? Wa : (w == 1) ? (Wa + 128 * DIN) : Wg;
            Bpack[idx] = f2bf(W[k * DIN + n]);
        }
    } else {
        int row = b - PACK_BLOCKS;
        if (tid < DIN) s[tid] = emb_rel[row * DIN + tid];
        __syncthreads();
        int j = tid & 127;
        const float* W = (tid < 128) ? (Wa + 256 * DIN) : (Wg + 128 * DIN);
        float acc = 0.f;
#pragma unroll 8
        for (int k = 0; k < DIN; k++) acc += s[k] * W[k * DIN + j];
        int pos = row * 256 + 8 * (j >> 2) + (j & 3) + ((tid < 128) ? 0 : 4);
        TaTg[pos] = f2bf(acc);
    }
}

// ---------------- K2: [MFMA entity GEMMs | bucket scatter] merged ----------
// gemm: operand-swapped MFMA, writes Pt (plain) and PhGh (interleaved rows of 256).
// scat: 4 triplets/thread via 3x int4, edge packed (h<<6)|r; deg strided 64B/counter.
__global__ __launch_bounds__(256) void k_mid(const float* __restrict__ X,
                                             const unsigned short* __restrict__ Bpack,
                                             const int* __restrict__ trip,
                                             const float* __restrict__ ba,
                                             const float* __restrict__ bg,
                                             unsigned short* __restrict__ Pt,
                                             unsigned short* __restrict__ PhGh,
                                             int* __restrict__ deg,
                                             int* __restrict__ elist) {
    __shared__ unsigned short As[64][136];
    int b = blockIdx.x;
    int tid = threadIdx.x;

    if (b < ENT_BLOCKS) {
        int m0 = b * 64;
        // coalesced stage of X tile as bf16
        for (int i = 0; i < 8; i++) {
            int v = tid + i * 256;
            int row = v >> 5;
            int c4 = v & 31;
            int gr = m0 + row;
            if (gr >= NUM_ENT) gr = NUM_ENT - 1;
            float4 x = *(const float4*)&X[gr * DIN + c4 * 4];
            ushort4 h;
            h.x = f2bf(x.x); h.y = f2bf(x.y); h.z = f2bf(x.z); h.w = f2bf(x.w);
            *(ushort4*)&As[row][c4 * 4] = h;
        }
        __syncthreads();

        int w = tid >> 6;
        int q = tid & 63;
        int quad = q >> 4;
        int lrow = w * 16 + (q & 15);
        int gr = m0 + lrow;

        bf16x8 a[4];
#pragma unroll
        for (int ks = 0; ks < 4; ks++)
            a[ks] = *(const bf16x8*)&As[lrow][ks * 32 + quad * 8];

        const bf16x8* Bp = (const bf16x8*)Bpack;
#pragma unroll
        for (int s = 0; s < 3; s++) {
            f32x4 acc[8];
#pragma unroll
            for (int t = 0; t < 8; t++) acc[t] = (f32x4){0.f, 0.f, 0.f, 0.f};
#pragma unroll
            for (int ks = 0; ks < 4; ks++) {
#pragma unroll
                for (int t = 0; t < 8; t++) {
                    bf16x8 wf = Bp[((s * 8 + t) * 4 + ks) * 64 + q];
                    acc[t] = __builtin_amdgcn_mfma_f32_16x16x32_bf16(wf, a[ks], acc[t], 0, 0, 0);
                }
            }
            if (gr < NUM_ENT) {
#pragma unroll
                for (int t = 0; t < 8; t++) {
                    int n0 = t * 16 + quad * 4;        // n0 % 4 == 0
                    float4 bb = make_float4(0.f, 0.f, 0.f, 0.f);
                    if (s == 0) bb = *(const float4*)&ba[n0];
                    if (s == 2) bb = *(const float4*)&bg[n0];
                    ushort4 o;
                    o.x = f2bf(acc[t][0] + bb.x);
                    o.y = f2bf(acc[t][1] + bb.y);
                    o.z = f2bf(acc[t][2] + bb.z);
                    o.w = f2bf(acc[t][3] + bb.w);
                    if (s == 0) {
                        *(ushort4*)&Pt[gr * DIN + n0] = o;
                    } else {
                        // interleaved: Ph at 2*n0, Gh at 2*n0+4 within row gr*256
                        *(ushort4*)&PhGh[gr * 256 + 2 * n0 + ((s == 1) ? 0 : 4)] = o;
                    }
                }
            }
        }
    } else {
        int i0 = (b - ENT_BLOCKS) * 1024 + tid * 4;   // 4 consecutive triplets
        if (i0 < NUM_TRI) {                           // NUM_TRI % 4 == 0
            const int4* tp = (const int4*)&trip[i0 * 3];   // 48B, 16B-aligned
            int4 A = tp[0], B4 = tp[1], C4 = tp[2];
            int hs[4] = {A.x, A.w, B4.z, C4.y};
            int rs[4] = {A.y, B4.x, B4.w, C4.z};
            int ts[4] = {A.z, B4.y, C4.x, C4.w};
#pragma unroll
            for (int u = 0; u < 4; u++) {
                int pos = atomicAdd(&deg[ts[u] * DEGS], 1);
                if (pos < CAP) elist[ts[u] * CAP + pos] = (hs[u] << 6) | rs[u];
            }
        }
    }
}

// ---------------- K3: fused per-tail pass, one 64-lane wave per tail ----------
// lanes 0-31 take even edges, 32-63 odd edges; merge is linear (exp-safe: |p|<=2).
// whole bucket's edge list loaded once (coalesced 256B) and distributed via shfl.
// per-half loop manually unrolled x2: both edges' gathers issued back-to-back (MLP=4).
// SHFL-DIVERGENCE RULE: divergent-trip loop iterations are half0-only (reads its
// own lanes: OK); the remainder can be half1-only, so its shfl MUST stay hoisted
// to the reconverged point before the `if` (exec-masked-lane read is undefined --
// produced absmax 2.39 when violated).
__global__ __launch_bounds__(256) void k_fused(const int* __restrict__ elist,
                                               const int* __restrict__ deg_arr,
                                               const unsigned short* __restrict__ Pt,
                                               const unsigned short* __restrict__ PhGh,
                                               const unsigned short* __restrict__ TaTg,
                                               const float* __restrict__ attn_vec,
                                               float* __restrict__ out) {
    int tid = threadIdx.x;
    int wv = tid >> 6;
    int lane = tid & 63;
    int half = lane >> 5;
    int q = lane & 31;
    int t = blockIdx.x * 4 + wv;
    int deg = deg_arr[t * DEGS];
    if (deg > CAP) deg = CAP;
    int c = q * 4;

    float4 pt4 = ldbf4(&Pt[t * DIN + c]);
    float4 av4 = *(const float4*)&attn_vec[c];
    float sumAv = av4.x + av4.y + av4.z + av4.w;
    float4 m2av = make_float4(-2.f * av4.x, -2.f * av4.y, -2.f * av4.z, -2.f * av4.w);

    // whole bucket in one coalesced load; slots >= deg never selected
    int eall = elist[t * CAP + lane];

    float l = 0.f;
    float4 acc = make_float4(0.f, 0.f, 0.f, 0.f);
    float4 sTa = make_float4(0.f, 0.f, 0.f, 0.f);
    float4 sTg = make_float4(0.f, 0.f, 0.f, 0.f);

    int it = half;
    for (; it + 2 < deg; it += 4) {
        int e0 = __shfl(eall, it);
        int e1 = __shfl(eall, it + 2);
        int h0 = e0 >> 6, r0 = e0 & 63;
        int h1 = e1 >> 6, r1 = e1 & 63;
        float4 ta0, tg0, ph0, gh0, ta1, tg1, ph1, gh1;
        ldbf8(&TaTg[r0 * 256 + q * 8], &ta0, &tg0);
        ldbf8(&PhGh[h0 * 256 + q * 8], &ph0, &gh0);
        ldbf8(&TaTg[r1 * 256 + q * 8], &ta1, &tg1);
        ldbf8(&PhGh[h1 * 256 + q * 8], &ph1, &gh1);

        sTa = f4add(sTa, f4add(ta0, ta1));
        sTg = f4add(sTg, f4add(tg0, tg1));
        float4 pa0 = f4add(ph0, ta0);
        float4 gm0 = f4add(gh0, tg0);
        float4 pa1 = f4add(ph1, ta1);
        float4 gm1 = f4add(gh1, tg1);
        float p0 = att_p(f4add(pt4, pa0), m2av, sumAv);
        float p1 = att_p(f4add(pt4, pa1), m2av, sumAv);
        p0 += __shfl_xor(p0, 1);
        p0 += __shfl_xor(p0, 2);
        p1 += __shfl_xor(p1, 1);
        p1 += __shfl_xor(p1, 2);
        float w0 = __expf(p0);
        float w1 = __expf(p1);
        l += w0 + w1;
        acc.x += w0 * gm0.x + w1 * gm1.x;
        acc.y += w0 * gm0.y + w1 * gm1.y;
        acc.z += w0 * gm0.z + w1 * gm1.z;
        acc.w += w0 * gm0.w + w1 * gm1.w;
    }
    // remainder: shfl hoisted to reconverged control flow (all 64 lanes execute);
    // lanes with it >= deg read a dummy legal index and discard the value.
    {
        int e = __shfl(eall, it & (CAP - 1));
        if (it < deg) {
            int h = e >> 6;
            int r = e & 63;
            float4 ta, tg, ph, gh;
            ldbf8(&TaTg[r * 256 + q * 8], &ta, &tg);
            ldbf8(&PhGh[h * 256 + q * 8], &ph, &gh);
            sTa = f4add(sTa, ta);
            sTg = f4add(sTg, tg);
            float4 pa = f4add(ph, ta);
            float4 gm = f4add(gh, tg);
            float p = att_p(f4add(pt4, pa), m2av, sumAv);
            p += __shfl_xor(p, 1);
            p += __shfl_xor(p, 2);
            float w = __expf(p);
            l += w;
            acc.x += w * gm.x; acc.y += w * gm.y; acc.z += w * gm.z; acc.w += w * gm.w;
        }
    }

    // merge the two halves (linear: no running max needed)
    l     += __shfl_xor(l, 32);
    acc.x += __shfl_xor(acc.x, 32);
    acc.y += __shfl_xor(acc.y, 32);
    acc.z += __shfl_xor(acc.z, 32);
    acc.w += __shfl_xor(acc.w, 32);
    sTa.x += __shfl_xor(sTa.x, 32);
    sTa.y += __shfl_xor(sTa.y, 32);
    sTa.z += __shfl_xor(sTa.z, 32);
    sTa.w += __shfl_xor(sTa.w, 32);
    sTg.x += __shfl_xor(sTg.x, 32);
    sTg.y += __shfl_xor(sTg.y, 32);
    sTg.z += __shfl_xor(sTg.z, 32);
    sTg.w += __shfl_xor(sTg.w, 32);

    // self edge: both halves compute identical values (merged inputs)
    {
        float inv = (deg > 0) ? __builtin_amdgcn_rcpf((float)deg) : 0.f;
        float4 pa, gm;
        ldbf8(&PhGh[t * 256 + q * 8], &pa, &gm);
        pa.x += sTa.x * inv; pa.y += sTa.y * inv; pa.z += sTa.z * inv; pa.w += sTa.w * inv;
        gm.x += sTg.x * inv; gm.y += sTg.y * inv; gm.z += sTg.z * inv; gm.w += sTg.w * inv;
        float p = att_p(f4add(pt4, pa), m2av, sumAv);
        p += __shfl_xor(p, 1);
        p += __shfl_xor(p, 2);
        float w = __expf(p);
        l += w;
        acc.x += w * gm.x; acc.y += w * gm.y; acc.z += w * gm.z; acc.w += w * gm.w;
    }
    float invl = 1.f / (l + 1e-16f);
    if (half == 0) {
        *(float4*)&out[t * DIN + c] =
            make_float4(acc.x * invl, acc.y * invl, acc.z * invl, acc.w * invl);
    }
}

extern "C" void kernel_launch(void* const* d_in, const int* in_sizes, int n_in,
                              void* d_out, int out_size, void* d_ws, size_t ws_size,
                              hipStream_t stream) {
    const float* emb_ent  = (const float*)d_in[0];
    const float* emb_rel  = (const float*)d_in[1];
    const int*   trip     = (const int*)d_in[2];
    const float* Wa       = (const float*)d_in[3];
    const float* ba       = (const float*)d_in[4];
    const float* attn_vec = (const float*)d_in[5];
    const float* Wg       = (const float*)d_in[6];
    const float* bg       = (const float*)d_in[7];
    float* out = (float*)d_out;

    // workspace layout: bf16 region then int region
    unsigned short* wsh = (unsigned short*)d_ws;
    unsigned short* Pt    = wsh;                      //  6,400,000 us
    unsigned short* PhGh  = wsh + 6400000;            // 12,800,000 us (interleaved)
    unsigned short* TaTg  = wsh + 19200000;           //     16,384 us (interleaved)
    unsigned short* Bpack = wsh + 19216384;           //     49,152
    int* deg   = (int*)(wsh + 19265536);              // 50,000*16 ints strided (3.2MB)
    int* elist = deg + 50000 * DEGS;                  // 50,000*64 int = 12.8 MB
    // total ~ 54.6 MB

    hipMemsetAsync(deg, 0, NUM_ENT * DEGS * sizeof(int), stream);

    k_prep<<<PREP_BLOCKS, 256, 0, stream>>>(emb_rel, Wa, Wg, Bpack, TaTg);

    k_mid<<<MID_BLOCKS, 256, 0, stream>>>(emb_ent, Bpack, trip, ba, bg,
                                          Pt, PhGh, deg, elist);

    k_fused<<<NUM_ENT / 4, 256, 0, stream>>>(elist, deg,
                                             Pt, PhGh, TaTg, attn_vec, out);
}

// Round 9
// 172.633 us; speedup vs baseline: 5.2651x; 1.0675x over previous
//
#include <hip/hip_runtime.h>
#include <math.h>

#define NUM_ENT  50000
#define NUM_REL  64
#define NUM_TRI  400000
#define DIN      128
#define CAP      64                      // per-tail bucket capacity (deg~Poisson(8))

// K1 partitions
#define PACK_BLOCKS  24                  // 24*256*8 = 49152 = 3*128*128
#define SMALL_BLOCKS 64
#define ZERO_BLOCKS  196                 // ceil(50000/256)
#define PREP_BLOCKS  (PACK_BLOCKS + SMALL_BLOCKS + ZERO_BLOCKS)

// K2: [scat | gemm] INTERLEAVED block mapping. 1173 = 3*391:
//   b%3==0 -> scat task b/3 (391 tasks); else gemm tile (b/3)*2 + b%3 - 1 (782).
// r1/r8 lesson: appending scat blocks after gemm blocks serializes the phases
// (dispatch order fills CUs with gemm first): 66us ~= 18 + 48. Interleaving
// makes them co-resident -> atomic stalls hide under MFMA.
#define SCAT_BLOCKS  391                 // ceil(400000/1024): 4 triplets/thread
#define ENT_BLOCKS   782                 // ceil(50000/64)
#define MID_BLOCKS   (SCAT_BLOCKS + ENT_BLOCKS)      // 1173 = 3*391

typedef __attribute__((ext_vector_type(8))) short bf16x8;
typedef __attribute__((ext_vector_type(8))) unsigned short u16x8;
typedef __attribute__((ext_vector_type(4))) float f32x4;

__device__ __forceinline__ float4 f4add(float4 a, float4 b) {
    return make_float4(a.x + b.x, a.y + b.y, a.z + b.z, a.w + b.w);
}

// fp32 -> bf16 bits, round-to-nearest-even
__device__ __forceinline__ unsigned short f2bf(float f) {
    unsigned u = __float_as_uint(f);
    unsigned r = ((u >> 16) & 1u) + 0x7fffu;
    return (unsigned short)((u + r) >> 16);
}
__device__ __forceinline__ float bf2f(unsigned short h) {
    return __uint_as_float(((unsigned)h) << 16);
}
__device__ __forceinline__ float4 ldbf4(const unsigned short* p) {
    ushort4 u = *(const ushort4*)p;
    return make_float4(bf2f(u.x), bf2f(u.y), bf2f(u.z), bf2f(u.w));
}
// load 8 interleaved bf16 with ONE 16B load -> two float4 (first 4, last 4)
__device__ __forceinline__ void ldbf8(const unsigned short* p, float4* lo, float4* hi) {
    u16x8 u = *(const u16x8*)p;
    *lo = make_float4(bf2f(u[0]), bf2f(u[1]), bf2f(u[2]), bf2f(u[3]));
    *hi = make_float4(bf2f(u[4]), bf2f(u[5]), bf2f(u[6]), bf2f(u[7]));
}

// attention dot with av folded in: sum_i tanh(x_i)*av_i
//   = sumAv + sum_i m2av_i * rcp(e^{2 x_i} + 1),   m2av = -2*av.
// Saturates correctly: x->+inf: rcp(inf)=0 -> av_i; x->-inf: rcp(1)=1 -> -av_i.
// Correctness validated rounds 7/8 (absmax 0.015625).
__device__ __forceinline__ float att_p(float4 x, float4 m2av, float sumAv) {
    float r0 = __builtin_amdgcn_rcpf(__expf(2.f * x.x) + 1.f);
    float r1 = __builtin_amdgcn_rcpf(__expf(2.f * x.y) + 1.f);
    float r2 = __builtin_amdgcn_rcpf(__expf(2.f * x.z) + 1.f);
    float r3 = __builtin_amdgcn_rcpf(__expf(2.f * x.w) + 1.f);
    return fmaf(m2av.x, r0, fmaf(m2av.y, r1, fmaf(m2av.z, r2, fmaf(m2av.w, r3, sumAv))));
}

// ---------------- K1: [pack W frags | rel tables (interleaved) | zero deg] ----------
// Bpack flat index: (((s*8 + t)*4 + ks)*64 + lane)*8 + j
//   holds W_s[k = ks*32 + (lane>>4)*8 + j][n = t*16 + (lane&15)] as bf16.
// TaTg row r (256 us): pos 8*(n>>2)+(n&3) = Ta[n], pos 8*(n>>2)+4+(n&3) = Tg[n].
__global__ __launch_bounds__(256) void k_prep(const float* __restrict__ emb_rel,
                                              const float* __restrict__ Wa,
                                              const float* __restrict__ Wg,
                                              unsigned short* __restrict__ Bpack,
                                              unsigned short* __restrict__ TaTg,
                                              int* __restrict__ deg) {
    __shared__ float s[DIN];
    int b = blockIdx.x;
    int tid = threadIdx.x;

    if (b < PACK_BLOCKS) {
        for (int i = 0; i < 8; i++) {
            int idx = b * 2048 + i * 256 + tid;       // < 49152
            int j    = idx & 7;
            int lane = (idx >> 3) & 63;
            int ks   = (idx >> 9) & 3;
            int t    = (idx >> 11) & 7;
            int w    = idx >> 14;
            int k = ks * 32 + ((lane >> 4) << 3) + j;
            int n = t * 16 + (lane & 15);
            const float* W = (w == 0) ? Wa : (w == 1) ? (Wa + 128 * DIN) : Wg;
            Bpack[idx] = f2bf(W[k * DIN + n]);
        }
    } else if (b < PACK_BLOCKS + SMALL_BLOCKS) {
        int row = b - PACK_BLOCKS;
        if (tid < DIN) s[tid] = emb_rel[row * DIN + tid];
        __syncthreads();
        int j = tid & 127;
        const float* W = (tid < 128) ? (Wa + 256 * DIN) : (Wg + 128 * DIN);
        float acc = 0.f;
#pragma unroll 8
        for (int k = 0; k < DIN; k++) acc += s[k] * W[k * DIN + j];
        int pos = row * 256 + 8 * (j >> 2) + (j & 3) + ((tid < 128) ? 0 : 4);
        TaTg[pos] = f2bf(acc);
    } else {
        int idx = (b - PACK_BLOCKS - SMALL_BLOCKS) * 256 + tid;
        if (idx < NUM_ENT) deg[idx] = 0;
    }
}

// ---------------- K2: [bucket scatter || MFMA entity GEMMs] interleaved ----------
// gemm: operand-swapped MFMA, writes Pt (plain) and PhGh (interleaved rows of 256).
// scat: 4 triplets/thread via 3x int4, edge packed (h<<6)|r, compact 4B deg counters
// (r8 falsified line-striding: 64B-strided counters were SLOWER, 66-69 vs 60-63).
__global__ __launch_bounds__(256) void k_mid(const float* __restrict__ X,
                                             const unsigned short* __restrict__ Bpack,
                                             const int* __restrict__ trip,
                                             const float* __restrict__ ba,
                                             const float* __restrict__ bg,
                                             unsigned short* __restrict__ Pt,
                                             unsigned short* __restrict__ PhGh,
                                             int* __restrict__ deg,
                                             int* __restrict__ elist) {
    __shared__ unsigned short As[64][136];
    int b = blockIdx.x;
    int tid = threadIdx.x;
    int third = b / 3;
    int rem = b - third * 3;

    if (rem == 0) {
        // ---- scatter task 'third' in [0, 391) ----
        int i0 = third * 1024 + tid * 4;              // 4 consecutive triplets
        if (i0 < NUM_TRI) {                           // NUM_TRI % 4 == 0
            const int4* tp = (const int4*)&trip[i0 * 3];   // 48B, 16B-aligned
            int4 A = tp[0], B4 = tp[1], C4 = tp[2];
            int hs[4] = {A.x, A.w, B4.z, C4.y};
            int rs[4] = {A.y, B4.x, B4.w, C4.z};
            int ts[4] = {A.z, B4.y, C4.x, C4.w};
#pragma unroll
            for (int u = 0; u < 4; u++) {
                int pos = atomicAdd(&deg[ts[u]], 1);
                if (pos < CAP) elist[ts[u] * CAP + pos] = (hs[u] << 6) | rs[u];
            }
        }
    } else {
        // ---- gemm tile in [0, 782) ----
        int tile = third * 2 + rem - 1;
        int m0 = tile * 64;
        // coalesced stage of X tile as bf16
        for (int i = 0; i < 8; i++) {
            int v = tid + i * 256;
            int row = v >> 5;
            int c4 = v & 31;
            int gr = m0 + row;
            if (gr >= NUM_ENT) gr = NUM_ENT - 1;
            float4 x = *(const float4*)&X[gr * DIN + c4 * 4];
            ushort4 h;
            h.x = f2bf(x.x); h.y = f2bf(x.y); h.z = f2bf(x.z); h.w = f2bf(x.w);
            *(ushort4*)&As[row][c4 * 4] = h;
        }
        __syncthreads();

        int w = tid >> 6;
        int q = tid & 63;
        int quad = q >> 4;
        int lrow = w * 16 + (q & 15);
        int gr = m0 + lrow;

        bf16x8 a[4];
#pragma unroll
        for (int ks = 0; ks < 4; ks++)
            a[ks] = *(const bf16x8*)&As[lrow][ks * 32 + quad * 8];

        const bf16x8* Bp = (const bf16x8*)Bpack;
#pragma unroll
        for (int s = 0; s < 3; s++) {
            f32x4 acc[8];
#pragma unroll
            for (int t = 0; t < 8; t++) acc[t] = (f32x4){0.f, 0.f, 0.f, 0.f};
#pragma unroll
            for (int ks = 0; ks < 4; ks++) {
#pragma unroll
                for (int t = 0; t < 8; t++) {
                    bf16x8 wf = Bp[((s * 8 + t) * 4 + ks) * 64 + q];
                    acc[t] = __builtin_amdgcn_mfma_f32_16x16x32_bf16(wf, a[ks], acc[t], 0, 0, 0);
                }
            }
            if (gr < NUM_ENT) {
#pragma unroll
                for (int t = 0; t < 8; t++) {
                    int n0 = t * 16 + quad * 4;        // n0 % 4 == 0
                    float4 bb = make_float4(0.f, 0.f, 0.f, 0.f);
                    if (s == 0) bb = *(const float4*)&ba[n0];
                    if (s == 2) bb = *(const float4*)&bg[n0];
                    ushort4 o;
                    o.x = f2bf(acc[t][0] + bb.x);
                    o.y = f2bf(acc[t][1] + bb.y);
                    o.z = f2bf(acc[t][2] + bb.z);
                    o.w = f2bf(acc[t][3] + bb.w);
                    if (s == 0) {
                        *(ushort4*)&Pt[gr * DIN + n0] = o;
                    } else {
                        // interleaved: Ph at 2*n0, Gh at 2*n0+4 within row gr*256
                        *(ushort4*)&PhGh[gr * 256 + 2 * n0 + ((s == 1) ? 0 : 4)] = o;
                    }
                }
            }
        }
    }
}

// ---------------- K3: fused per-tail pass, one 64-lane wave per tail ----------
// lanes 0-31 take even edges, 32-63 odd edges; merge is linear (exp-safe: |p|<=2).
// whole bucket's edge list loaded once (coalesced 256B) and distributed via shfl.
// per-half loop manually unrolled x2: both edges' gathers issued back-to-back (MLP=4).
// SHFL-DIVERGENCE RULE: divergent-trip loop iterations are half0-only (reads its
// own lanes: OK); the remainder can be half1-only, so its shfl MUST stay hoisted
// to the reconverged point before the `if` (exec-masked-lane read is undefined --
// produced absmax 2.39 when violated).
__global__ __launch_bounds__(256) void k_fused(const int* __restrict__ elist,
                                               const int* __restrict__ deg_arr,
                                               const unsigned short* __restrict__ Pt,
                                               const unsigned short* __restrict__ PhGh,
                                               const unsigned short* __restrict__ TaTg,
                                               const float* __restrict__ attn_vec,
                                               float* __restrict__ out) {
    int tid = threadIdx.x;
    int wv = tid >> 6;
    int lane = tid & 63;
    int half = lane >> 5;
    int q = lane & 31;
    int t = blockIdx.x * 4 + wv;
    int deg = deg_arr[t];
    if (deg > CAP) deg = CAP;
    int c = q * 4;

    float4 pt4 = ldbf4(&Pt[t * DIN + c]);
    float4 av4 = *(const float4*)&attn_vec[c];
    float sumAv = av4.x + av4.y + av4.z + av4.w;
    float4 m2av = make_float4(-2.f * av4.x, -2.f * av4.y, -2.f * av4.z, -2.f * av4.w);

    // whole bucket in one coalesced load; slots >= deg never selected
    int eall = elist[t * CAP + lane];

    float l = 0.f;
    float4 acc = make_float4(0.f, 0.f, 0.f, 0.f);
    float4 sTa = make_float4(0.f, 0.f, 0.f, 0.f);
    float4 sTg = make_float4(0.f, 0.f, 0.f, 0.f);

    int it = half;
    for (; it + 2 < deg; it += 4) {
        int e0 = __shfl(eall, it);
        int e1 = __shfl(eall, it + 2);
        int h0 = e0 >> 6, r0 = e0 & 63;
        int h1 = e1 >> 6, r1 = e1 & 63;
        float4 ta0, tg0, ph0, gh0, ta1, tg1, ph1, gh1;
        ldbf8(&TaTg[r0 * 256 + q * 8], &ta0, &tg0);
        ldbf8(&PhGh[h0 * 256 + q * 8], &ph0, &gh0);
        ldbf8(&TaTg[r1 * 256 + q * 8], &ta1, &tg1);
        ldbf8(&PhGh[h1 * 256 + q * 8], &ph1, &gh1);

        sTa = f4add(sTa, f4add(ta0, ta1));
        sTg = f4add(sTg, f4add(tg0, tg1));
        float4 pa0 = f4add(ph0, ta0);
        float4 gm0 = f4add(gh0, tg0);
        float4 pa1 = f4add(ph1, ta1);
        float4 gm1 = f4add(gh1, tg1);
        float p0 = att_p(f4add(pt4, pa0), m2av, sumAv);
        float p1 = att_p(f4add(pt4, pa1), m2av, sumAv);
        p0 += __shfl_xor(p0, 1);
        p0 += __shfl_xor(p0, 2);
        p1 += __shfl_xor(p1, 1);
        p1 += __shfl_xor(p1, 2);
        float w0 = __expf(p0);
        float w1 = __expf(p1);
        l += w0 + w1;
        acc.x += w0 * gm0.x + w1 * gm1.x;
        acc.y += w0 * gm0.y + w1 * gm1.y;
        acc.z += w0 * gm0.z + w1 * gm1.z;
        acc.w += w0 * gm0.w + w1 * gm1.w;
    }
    // remainder: shfl hoisted to reconverged control flow (all 64 lanes execute);
    // lanes with it >= deg read a dummy legal index and discard the value.
    {
        int e = __shfl(eall, it & (CAP - 1));
        if (it < deg) {
            int h = e >> 6;
            int r = e & 63;
            float4 ta, tg, ph, gh;
            ldbf8(&TaTg[r * 256 + q * 8], &ta, &tg);
            ldbf8(&PhGh[h * 256 + q * 8], &ph, &gh);
            sTa = f4add(sTa, ta);
            sTg = f4add(sTg, tg);
            float4 pa = f4add(ph, ta);
            float4 gm = f4add(gh, tg);
            float p = att_p(f4add(pt4, pa), m2av, sumAv);
            p += __shfl_xor(p, 1);
            p += __shfl_xor(p, 2);
            float w = __expf(p);
            l += w;
            acc.x += w * gm.x; acc.y += w * gm.y; acc.z += w * gm.z; acc.w += w * gm.w;
        }
    }

    // merge the two halves (linear: no running max needed)
    l     += __shfl_xor(l, 32);
    acc.x += __shfl_xor(acc.x, 32);
    acc.y += __shfl_xor(acc.y, 32);
    acc.z += __shfl_xor(acc.z, 32);
    acc.w += __shfl_xor(acc.w, 32);
    sTa.x += __shfl_xor(sTa.x, 32);
    sTa.y += __shfl_xor(sTa.y, 32);
    sTa.z += __shfl_xor(sTa.z, 32);
    sTa.w += __shfl_xor(sTa.w, 32);
    sTg.x += __shfl_xor(sTg.x, 32);
    sTg.y += __shfl_xor(sTg.y, 32);
    sTg.z += __shfl_xor(sTg.z, 32);
    sTg.w += __shfl_xor(sTg.w, 32);

    // self edge: both halves compute identical values (merged inputs)
    {
        float inv = (deg > 0) ? __builtin_amdgcn_rcpf((float)deg) : 0.f;
        float4 pa, gm;
        ldbf8(&PhGh[t * 256 + q * 8], &pa, &gm);
        pa.x += sTa.x * inv; pa.y += sTa.y * inv; pa.z += sTa.z * inv; pa.w += sTa.w * inv;
        gm.x += sTg.x * inv; gm.y += sTg.y * inv; gm.z += sTg.z * inv; gm.w += sTg.w * inv;
        float p = att_p(f4add(pt4, pa), m2av, sumAv);
        p += __shfl_xor(p, 1);
        p += __shfl_xor(p, 2);
        float w = __expf(p);
        l += w;
        acc.x += w * gm.x; acc.y += w * gm.y; acc.z += w * gm.z; acc.w += w * gm.w;
    }
    float invl = 1.f / (l + 1e-16f);
    if (half == 0) {
        *(float4*)&out[t * DIN + c] =
            make_float4(acc.x * invl, acc.y * invl, acc.z * invl, acc.w * invl);
    }
}

extern "C" void kernel_launch(void* const* d_in, const int* in_sizes, int n_in,
                              void* d_out, int out_size, void* d_ws, size_t ws_size,
                              hipStream_t stream) {
    const float* emb_ent  = (const float*)d_in[0];
    const float* emb_rel  = (const float*)d_in[1];
    const int*   trip     = (const int*)d_in[2];
    const float* Wa       = (const float*)d_in[3];
    const float* ba       = (const float*)d_in[4];
    const float* attn_vec = (const float*)d_in[5];
    const float* Wg       = (const float*)d_in[6];
    const float* bg       = (const float*)d_in[7];
    float* out = (float*)d_out;

    // workspace layout: bf16 region then int region
    unsigned short* wsh = (unsigned short*)d_ws;
    unsigned short* Pt    = wsh;                      //  6,400,000 us
    unsigned short* PhGh  = wsh + 6400000;            // 12,800,000 us (interleaved)
    unsigned short* TaTg  = wsh + 19200000;           //     16,384 us (interleaved)
    unsigned short* Bpack = wsh + 19216384;           //     49,152
    int* deg   = (int*)(wsh + 19265536);              //     50,000 (zeroed in K1)
    int* elist = deg + 50000;                         // 50,000*64 int = 12.8 MB
    // total ~ 51.6 MB

    k_prep<<<PREP_BLOCKS, 256, 0, stream>>>(emb_rel, Wa, Wg, Bpack, TaTg, deg);

    k_mid<<<MID_BLOCKS, 256, 0, stream>>>(emb_ent, Bpack, trip, ba, bg,
                                          Pt, PhGh, deg, elist);

    k_fused<<<NUM_ENT / 4, 256, 0, stream>>>(elist, deg,
                                             Pt, PhGh, TaTg, attn_vec, out);
}